// Round 4
// baseline (1719.995 us; speedup 1.0000x reference)
//
#include <hip/hip_runtime.h>

typedef _Float16 half_t;
typedef _Float16 h2f __attribute__((ext_vector_type(2)));
typedef unsigned int uint32;

#define NTILE 128
#define SHIFT 2.0794415416798357f   // log(8) folded into every eo, repaid in combine

#if __has_builtin(__builtin_amdgcn_fdot2)
#define FDOT2(p, e, acc) __builtin_amdgcn_fdot2((p), (e), (acc), false)
#else
#define FDOT2(p, e, acc) fmaf((float)(p).x, (float)(e).x, fmaf((float)(p).y, (float)(e).y, (acc)))
#endif

__device__ __forceinline__ h2f u2h(uint32 u) { return __builtin_bit_cast(h2f, u); }
__device__ __forceinline__ uint32 pack2(float a, float b) {
    return (uint32)__builtin_bit_cast(unsigned short, (half_t)a)
         | ((uint32)__builtin_bit_cast(unsigned short, (half_t)b) << 16);
}

// global -> regs, one 16-step tile (2048 floats, coalesced)
#define LOADR(TK) do {                                                              \
    const float4* g_ = (const float4*)(obsB + (size_t)(FW ? (TK) * 2048             \
                                                           : (4080 - 16 * (TK)) * 128)); \
    r0 = g_[tid]; r1 = g_[tid + 128]; r2 = g_[tid + 256]; r3 = g_[tid + 384];       \
} while (0)

// regs -> eo LDS tile (fp16, exp applied at stage time, off the recurrence path)
#define STORE_EO(TK) do {                                                           \
    uint2* d_ = (uint2*)(eoL + (((TK) & 1) << 10));                                 \
    uint2 p_;                                                                       \
    p_.x = pack2(__expf(r0.x - SHIFT), __expf(r0.y - SHIFT));                       \
    p_.y = pack2(__expf(r0.z - SHIFT), __expf(r0.w - SHIFT));                       \
    d_[tid] = p_;                                                                   \
    p_.x = pack2(__expf(r1.x - SHIFT), __expf(r1.y - SHIFT));                       \
    p_.y = pack2(__expf(r1.z - SHIFT), __expf(r1.w - SHIFT));                       \
    d_[tid + 128] = p_;                                                             \
    p_.x = pack2(__expf(r2.x - SHIFT), __expf(r2.y - SHIFT));                       \
    p_.y = pack2(__expf(r2.z - SHIFT), __expf(r2.w - SHIFT));                       \
    d_[tid + 256] = p_;                                                             \
    p_.x = pack2(__expf(r3.x - SHIFT), __expf(r3.y - SHIFT));                       \
    p_.y = pack2(__expf(r3.z - SHIFT), __expf(r3.w - SHIFT));                       \
    d_[tid + 384] = p_;                                                             \
} while (0)

// One step. Phases (compile-time PH = n mod 4):
//  PH0: measure max(state) via one LDS atomicMax (off critical path)
//  PH1: read measured max (ordered by PH0's barrier), rs = rcp(M), fold into eo, L += log M
//  PH2: reset the max slot (ordered by PH1's barrier)
#define STEP(PH)  do {                                                              \
    /* ---- pre-barrier: produce & publish this step's shared vector ---- */        \
    float e = (float)__builtin_bit_cast(half_t, eo_u);                              \
    if (PH == 1) {                                                                  \
        const float M = __uint_as_float(*wred);                                     \
        Lacc += __logf(M);                                                          \
        e *= __builtin_amdgcn_rcpf(M);                                              \
    }                                                                               \
    if (PH == 2) { if (tid == 0) *wred = 0u; }                                      \
    float wv = FW ? pv : pv * e;                                                    \
    if (PH == 0) { if (FW && n == 0) wv = e;                                        \
                   atomicMax(wred, __float_as_uint(wv)); }                          \
    PbufH[((n & 1) << 7) + tid] = __builtin_bit_cast(unsigned short, (half_t)wv);   \
    __syncthreads();                                                                \
    /* ---- post-barrier: broadcast reads + 64 dot2 per lane ---- */                \
    {                                                                               \
        const uint4* q4 = (const uint4*)(Pbuf + ((n & 1) << 6));                    \
        uint4 q[16];                                                                \
        _Pragma("unroll") for (int c = 0; c < 16; ++c) q[c] = q4[c];                \
        const int n1 = n + 1;                                                       \
        const int row1 = FW ? (n1 & 15) : (15 - (n1 & 15));                         \
        eo_u = eoHW[(((n1 >> 4) & 1) << 11) + (row1 << 7) + tid];  /* prefetch */   \
        float a0 = 0.f, a1 = 0.f, a2 = 0.f, a3 = 0.f;                               \
        _Pragma("unroll") for (int c = 0; c < 16; ++c) {                            \
            a0 = FDOT2(u2h(q[c].x), ea[4*c+0], a0);                                 \
            a1 = FDOT2(u2h(q[c].y), ea[4*c+1], a1);                                 \
            a2 = FDOT2(u2h(q[c].z), ea[4*c+2], a2);                                 \
            a3 = FDOT2(u2h(q[c].w), ea[4*c+3], a3);                                 \
        }                                                                           \
        const float s = (a0 + a1) + (a2 + a3);                                      \
        float npv = FW ? s * e : s;                                                 \
        if (PH == 0) { if (FW && n == 0) npv = e; }                                 \
        pv = npv;                                                                   \
    }                                                                               \
    ++n;                                                                            \
} while (0)

template <bool FW>
__device__ __forceinline__ void run_chain(const float* __restrict__ obsB,
                                          const float* __restrict__ trans,
                                          float* __restrict__ ws, int b,
                                          uint32* Pbuf, uint32* eoL, uint32* wred)
{
    const int tid = threadIdx.x;                    // 0..127 (2 waves)
    unsigned short* PbufH = (unsigned short*)Pbuf;
    const unsigned short* eoHW = (const unsigned short*)eoL;

    // exp(A) fragment: lane owns column tid (fwd) / row tid (bwd), 64 h2f pairs
    h2f ea[64];
    #pragma unroll
    for (int k = 0; k < 64; ++k) {
        h2f t;
        if (FW) {
            t.x = (half_t)__expf(trans[(2*k    ) * 128 + tid]);
            t.y = (half_t)__expf(trans[(2*k + 1) * 128 + tid]);
        } else {
            t.x = (half_t)__expf(trans[tid * 128 + 2*k    ]);
            t.y = (half_t)__expf(trans[tid * 128 + 2*k + 1]);
        }
        ea[k] = t;
    }

    float4 r0, r1, r2, r3;
    LOADR(0);
    STORE_EO(0);
    LOADR(1);
    if (tid == 0) *wred = 0u;
    __syncthreads();

    unsigned short eo_u = eoHW[((FW ? 0 : 15) << 7) + tid];
    float pv   = FW ? 0.f : 1.f;   // bwd: Q_4095 = 1
    float Lacc = 0.f;
    int n = 0;

    for (int tile = 0; tile < NTILE; ++tile) {
        if (tile + 1 < NTILE) {
            STORE_EO(tile + 1);                 // stage one tile ahead (dbuf)
            if (tile + 2 < NTILE) LOADR(tile + 2);
        }
        #pragma unroll 1
        for (int g = 0; g < 4; ++g) {
            STEP(0); STEP(1); STEP(2); STEP(3);
        }
    }

    // halves to workspace: Pm[64][128] | Qm[64][128] | Lf[64] | Lb[64]
    ws[(FW ? 0 : 8192) + b * 128 + tid] = pv;
    if (tid == 0) ws[(FW ? 16384 : 16448) + b] = Lacc;
}

__global__ __launch_bounds__(128, 1)
void crf_half2(const float* __restrict__ obs, const float* __restrict__ trans,
               float* __restrict__ ws)
{
    __shared__ __align__(16) uint32 Pbuf[128];   // 2 x 128 fp16 state values
    __shared__ __align__(16) uint32 eoL[2048];   // 2 x (16 x 128) fp16 eo tiles
    __shared__ uint32 wred;
    const bool fw = blockIdx.x < 64;
    const int  b  = fw ? blockIdx.x : blockIdx.x - 64;
    const float* obsB = obs + (size_t)b * 4096 * 128;
    if (fw) run_chain<true >(obsB, trans, ws, b, Pbuf, eoL, &wred);
    else    run_chain<false>(obsB, trans, ws, b, Pbuf, eoL, &wred);
}

__global__ __launch_bounds__(64)
void crf_combine(const float* __restrict__ ws, float* __restrict__ out)
{
    const int b = blockIdx.x, l = threadIdx.x;
    const float* Pm = ws;
    const float* Qm = ws + 8192;
    float s = Pm[b * 128 + 2*l] * Qm[b * 128 + 2*l]
            + Pm[b * 128 + 2*l + 1] * Qm[b * 128 + 2*l + 1];
    s += __shfl_xor(s, 1);
    s += __shfl_xor(s, 2);
    s += __shfl_xor(s, 4);
    s += __shfl_xor(s, 8);
    s += __shfl_xor(s, 16);
    s += __shfl_xor(s, 32);
    if (l == 0)
        out[b] = -(__logf(s) + ws[16384 + b] + ws[16448 + b] + 4096.0f * SHIFT);
}

extern "C" void kernel_launch(void* const* d_in, const int* in_sizes, int n_in,
                              void* d_out, int out_size, void* d_ws, size_t ws_size,
                              hipStream_t stream) {
    const float* obs   = (const float*)d_in[0];   // [64, 4096, 128] fp32
    const float* trans = (const float*)d_in[1];   // [128, 128] fp32
    float* out = (float*)d_out;                   // [64] fp32
    float* ws  = (float*)d_ws;                    // >= 16512 floats
    hipLaunchKernelGGL(crf_half2,   dim3(128), dim3(128), 0, stream, obs, trans, ws);
    hipLaunchKernelGGL(crf_combine, dim3(64),  dim3(64),  0, stream, ws, out);
}

// Round 6
// 1215.114 us; speedup vs baseline: 1.4155x; 1.4155x over previous
//
#include <hip/hip_runtime.h>

typedef _Float16 half_t;
typedef _Float16 h8 __attribute__((ext_vector_type(8)));
typedef _Float16 h2 __attribute__((ext_vector_type(2)));
typedef float f4 __attribute__((ext_vector_type(4)));
typedef unsigned int uint32;

#define SHIFT 2.0794415416798357f   // log(8) folded into every eo, repaid at combine
// ws float offsets / layout:  X[64][128] | Q[64][128] | Lf[64] | Lb[64] | pad | eo16
#define WX 0
#define WQ 8192
#define WLF 16384
#define WLB 16448
#define EO_BYTE_OFF 66560u
#define FAST_WS_BYTES (EO_BYTE_OFF + (67108864u))   // eo = 4cg*4096t*64l*64B

__device__ __forceinline__ h2 pkrtz(float a, float b) {
    return __builtin_bit_cast(h2, __builtin_amdgcn_cvt_pkrtz(a, b));
}

// ============================ FAST PATH =====================================

// Kernel 1: eo16[cg][t][lane][32 halves] = fp16 exp(obs - SHIFT), permuted into
// the exact per-lane MFMA D-layout order kernel 2 consumes (lane l=q*16+n owns
// chain n, states 16*mt+4*q+r; half index h=4*mt+r). Output-contiguous mapping.
__global__ __launch_bounds__(256)
void eo_prep(const float* __restrict__ obs, uint32* __restrict__ eo)
{
    const int nth = gridDim.x * blockDim.x;
    for (int d = blockIdx.x * blockDim.x + threadIdx.x; d < (1 << 24); d += nth) {
        const int hd = d & 15, l = (d >> 4) & 63, t = (d >> 10) & 4095, cg = d >> 22;
        const int q = l >> 4, n = l & 15;
        const int mt = hd >> 1, rr = (hd & 1) * 2;
        const int s = mt * 16 + q * 4 + rr;
        const int b = cg * 16 + n;
        const float2 o = *(const float2*)&obs[((((size_t)b << 12) + t) << 7) + s];
        h2 p = pkrtz(__expf(o.x - SHIFT), __expf(o.y - SHIFT));
        eo[d] = __builtin_bit_cast(uint32, p);
    }
}

// One recurrence step (single wave, barrier-free; in-order DS pipe orders the
// write->read of Sb). P = it%4 (static). Renorm measured+applied at P==3.
#define STEP(P) do {                                                               \
    /* W = fp16(D) * eo (eo already includes exp and SHIFT) */                     \
    h2 W[16];                                                                      \
    { const uint32* ep = (const uint32*)&er[P][0];                                 \
      _Pragma("unroll") for (int mt = 0; mt < 8; ++mt) {                           \
        h2 p0 = pkrtz(D[mt].x, D[mt].y);                                           \
        h2 p1 = pkrtz(D[mt].z, D[mt].w);                                           \
        W[2*mt]   = p0 * __builtin_bit_cast(h2, ep[2*mt]);                         \
        W[2*mt+1] = p1 * __builtin_bit_cast(h2, ep[2*mt+1]);                       \
      } }                                                                          \
    if ((P) == 3) {  /* per-chain renorm: max over 32 local + lanes ^16,^32 */     \
        h2 mx = W[0];                                                              \
        _Pragma("unroll") for (int i = 1; i < 16; ++i)                             \
            mx = __builtin_elementwise_max(mx, W[i]);                              \
        float M = fmaxf((float)mx.x, (float)mx.y);                                 \
        M = fmaxf(M, __shfl_xor(M, 16));                                           \
        M = fmaxf(M, __shfl_xor(M, 32));                                           \
        Lacc += __logf(M);                                                         \
        const half_t rh = (half_t)__builtin_amdgcn_rcpf(M);                        \
        h2 r2; r2.x = rh; r2.y = rh;                                               \
        _Pragma("unroll") for (int i = 0; i < 16; ++i) W[i] = W[i] * r2;           \
    }                                                                              \
    /* publish W: state s -> Sb[chunk s>>3][chain n][s&7] (8B writes) */           \
    _Pragma("unroll") for (int mt = 0; mt < 8; ++mt) {                             \
        uint2 wv; wv.x = __builtin_bit_cast(uint32, W[2*mt]);                      \
        wv.y = __builtin_bit_cast(uint32, W[2*mt+1]);                              \
        *(uint2*)&Sb[mt * 256 + wbase] = wv;                                       \
    }                                                                              \
    /* prefetch eo for it+4 into this ring slot */                                 \
    { const int itn = it + 4;                                                      \
      const int te = FW ? itn : (4095 - itn);                                      \
      const uint4* gp = (const uint4*)(eo + (((size_t)cg << 22)                    \
                                     + ((size_t)te << 10) + (l << 4)));            \
      er[P][0] = gp[0]; er[P][1] = gp[1]; er[P][2] = gp[2]; er[P][3] = gp[3]; }    \
    /* read B fragments (16B, conflict-free) and run 32 MFMAs */                   \
    _Pragma("unroll") for (int kc = 0; kc < 4; ++kc)                               \
        Bf[kc] = __builtin_bit_cast(h8, *(const uint4*)&Sb[kc * 512 + rbase]);     \
    _Pragma("unroll") for (int mt = 0; mt < 8; ++mt) {                             \
        f4 acc = {0.f, 0.f, 0.f, 0.f};                                             \
        acc = __builtin_amdgcn_mfma_f32_16x16x32_f16(Af[mt][0], Bf[0], acc, 0,0,0);\
        acc = __builtin_amdgcn_mfma_f32_16x16x32_f16(Af[mt][1], Bf[1], acc, 0,0,0);\
        acc = __builtin_amdgcn_mfma_f32_16x16x32_f16(Af[mt][2], Bf[2], acc, 0,0,0);\
        acc = __builtin_amdgcn_mfma_f32_16x16x32_f16(Af[mt][3], Bf[3], acc, 0,0,0);\
        D[mt] = acc;                                                               \
    }                                                                              \
    it += 1;                                                                       \
} while (0)

template <bool FW>
__device__ __forceinline__ void chain(const uint32* __restrict__ eo,
                                      const float* __restrict__ trans,
                                      float* __restrict__ ws,
                                      half_t* Sb, int cg, int NIT)
{
    const int l = threadIdx.x & 63;
    const int q = l >> 4, n = l & 15;
    const int wbase = (q >> 1) * 128 + n * 8 + 4 * (q & 1);
    const int rbase = q * 128 + n * 8;

    // exp(A) MFMA A-fragments (constant; loaded once). fwd: D = eA^T * S ->
    // A[m][k] = eA[k][m]. bwd: D = eA * W -> A[m][k] = eA[m][k].
    h8 Af[8][4];
    #pragma unroll
    for (int mt = 0; mt < 8; ++mt)
        #pragma unroll
        for (int kc = 0; kc < 4; ++kc) {
            h8 a;
            #pragma unroll
            for (int j = 0; j < 8; ++j) {
                const int k = kc * 32 + q * 8 + j;
                const int m = mt * 16 + n;
                const float v = FW ? trans[k * 128 + m] : trans[m * 128 + k];
                a[j] = (half_t)__expf(v);
            }
            Af[mt][kc] = a;
        }

    // eo lookahead ring: 4 steps deep (lane-private, contiguous 64B per step)
    uint4 er[4][4];
    #pragma unroll
    for (int p = 0; p < 4; ++p) {
        const int te = FW ? p : (4095 - p);
        const uint4* gp = (const uint4*)(eo + (((size_t)cg << 22)
                                       + ((size_t)te << 10) + (l << 4)));
        er[p][0] = gp[0]; er[p][1] = gp[1]; er[p][2] = gp[2]; er[p][3] = gp[3];
    }

    f4 D[8];
    #pragma unroll
    for (int mt = 0; mt < 8; ++mt) D[mt] = (f4){1.f, 1.f, 1.f, 1.f};  // X0 = 1
    h8 Bf[4];
    float Lacc = 0.f;
    int it = 0;

    #pragma unroll 1
    for (int g = 0; g < (NIT >> 2); ++g) { STEP(0); STEP(1); STEP(2); STEP(3); }
    if (NIT & 3) { STEP(0); STEP(1); STEP(2); }   // bwd tail (2047 = 511*4 + 3)

    // final state (fp32, D layout) -> ws
    float* Xo = ws + (FW ? WX : WQ) + ((cg * 16 + n) << 7);
    #pragma unroll
    for (int mt = 0; mt < 8; ++mt)
        *(f4*)&Xo[mt * 16 + q * 4] = D[mt];
    if (q == 0) ws[(FW ? WLF : WLB) + cg * 16 + n] = Lacc;
}

__global__ __launch_bounds__(64, 1)
void crf_mfma(const uint32* __restrict__ eo, const float* __restrict__ trans,
              float* __restrict__ ws)
{
    __shared__ __align__(16) half_t Sb[2048];   // [chunk 0..15][chain 0..15][8]
    const int bid = blockIdx.x;
    if (bid < 4) chain<true >(eo, trans, ws, Sb, bid, 2048);      // eo 0..2047
    else         chain<false>(eo, trans, ws, Sb, bid - 4, 2047);  // eo 4095..2049
}

// Z = sum_s X_2048[s] * eo_2048[s] * Q_2048[s]; out = -(log Z + Lf + Lb + 4096*SHIFT)
__global__ __launch_bounds__(64)
void crf_comb(const float* __restrict__ obs, const float* __restrict__ ws,
              float* __restrict__ out)
{
    const int b = blockIdx.x, l = threadIdx.x;
    const int s0 = 2 * l;
    const float2 o = *(const float2*)&obs[((((size_t)b << 12) + 2048) << 7) + s0];
    const float e0 = __expf(o.x - SHIFT), e1 = __expf(o.y - SHIFT);
    float v = ws[WX + b * 128 + s0] * e0 * ws[WQ + b * 128 + s0]
            + ws[WX + b * 128 + s0 + 1] * e1 * ws[WQ + b * 128 + s0 + 1];
    v += __shfl_xor(v, 1);  v += __shfl_xor(v, 2);  v += __shfl_xor(v, 4);
    v += __shfl_xor(v, 8);  v += __shfl_xor(v, 16); v += __shfl_xor(v, 32);
    if (l == 0)
        out[b] = -(__logf(v) + ws[WLF + b] + ws[WLB + b] + 4096.0f * SHIFT);
}

// ======================= FALLBACK (R3, ws too small) ========================

typedef _Float16 h2f __attribute__((ext_vector_type(2)));
#define FTILE 16
#define FNTILE 128

#if __has_builtin(__builtin_amdgcn_fdot2)
#define FDOT2(p, e, acc) __builtin_amdgcn_fdot2((p), (e), (acc), false)
#else
#define FDOT2(p, e, acc) fmaf((float)(p).x, (float)(e).x, fmaf((float)(p).y, (float)(e).y, (acc)))
#endif

__device__ __forceinline__ h2f u2h(uint32 u) { return __builtin_bit_cast(h2f, u); }
__device__ __forceinline__ uint32 f2h(float f) {
    return (uint32)__builtin_bit_cast(unsigned short, (half_t)f);
}

#define FSTEP(N0, APPLY, MEAS)  do {                                                \
    const int row_ = fw ? ((N0) & (FTILE - 1)) : ((FTILE - 1) - ((N0) & (FTILE - 1))); \
    const float2 o2_ = *(const float2*)&obsL[(((N0) >> 4) & 1) * (FTILE * 128) + (row_ << 7) + (l << 1)]; \
    float e0_ = __expf(o2_.x - SHIFT);                                              \
    float e1_ = __expf(o2_.y - SHIFT);                                              \
    if (APPLY) { e0_ *= rs; e1_ *= rs; }                                            \
    float w0_, w1_;                                                                 \
    if (fw) { w0_ = pv0; w1_ = pv1; } else { w0_ = pv0 * e0_; w1_ = pv1 * e1_; }    \
    Pl[l] = (f2h(w1_) << 16) | f2h(w0_);                                            \
    float a0_=0.f,a1_=0.f,a2_=0.f,a3_=0.f,b0_=0.f,b1_=0.f,b2_=0.f,b3_=0.f;          \
    _Pragma("unroll")                                                               \
    for (int c_ = 0; c_ < 16; ++c_) {                                               \
        const uint4 q_ = ((const uint4*)Pl)[c_];                                    \
        const h2f p0_ = u2h(q_.x), p1_ = u2h(q_.y), p2_ = u2h(q_.z), p3_ = u2h(q_.w); \
        a0_ = FDOT2(p0_, eA[4*c_+0], a0_);                                          \
        a1_ = FDOT2(p1_, eA[4*c_+1], a1_);                                          \
        a2_ = FDOT2(p2_, eA[4*c_+2], a2_);                                          \
        a3_ = FDOT2(p3_, eA[4*c_+3], a3_);                                          \
        b0_ = FDOT2(p0_, eB[4*c_+0], b0_);                                          \
        b1_ = FDOT2(p1_, eB[4*c_+1], b1_);                                          \
        b2_ = FDOT2(p2_, eB[4*c_+2], b2_);                                          \
        b3_ = FDOT2(p3_, eB[4*c_+3], b3_);                                          \
    }                                                                               \
    const float s0_ = (a0_ + a1_) + (a2_ + a3_);                                    \
    const float s1_ = (b0_ + b1_) + (b2_ + b3_);                                    \
    if (fw) { pv0 = s0_ * e0_; pv1 = s1_ * e1_; } else { pv0 = s0_; pv1 = s1_; }    \
    if (MEAS) {                                                                     \
        float m_ = fmaxf(pv0, pv1);                                                 \
        m_ = fmaxf(m_, __shfl_xor(m_, 1));                                          \
        m_ = fmaxf(m_, __shfl_xor(m_, 2));                                          \
        m_ = fmaxf(m_, __shfl_xor(m_, 4));                                          \
        m_ = fmaxf(m_, __shfl_xor(m_, 8));                                          \
        m_ = fmaxf(m_, __shfl_xor(m_, 16));                                         \
        m_ = fmaxf(m_, __shfl_xor(m_, 32));                                         \
        rs = __builtin_amdgcn_rcpf(m_);                                             \
        Lacc += __logf(m_);                                                         \
    }                                                                               \
} while (0)

#define FLOADR(TK) do {                                                             \
    const float4* g_ = (const float4*)(obsB + (size_t)(fw ? (TK) * (FTILE * 128)    \
                                      : (4096 - FTILE * ((TK) + 1)) * 128));        \
    r0 = g_[l];       r1 = g_[l + 64];  r2 = g_[l + 128]; r3 = g_[l + 192];         \
    r4 = g_[l + 256]; r5 = g_[l + 320]; r6 = g_[l + 384]; r7 = g_[l + 448];         \
} while (0)

#define FSTORER(TK) do {                                                            \
    float4* s_ = (float4*)&obsL[((TK) & 1) * (FTILE * 128)];                        \
    s_[l] = r0;       s_[l + 64] = r1;  s_[l + 128] = r2; s_[l + 192] = r3;         \
    s_[l + 256] = r4; s_[l + 320] = r5; s_[l + 384] = r6; s_[l + 448] = r7;         \
} while (0)

__global__ __launch_bounds__(64, 1)
void crf_half_fb(const float* __restrict__ obs, const float* __restrict__ trans,
                 float* __restrict__ ws)
{
    __shared__ __align__(16) uint32 Pl[64];
    __shared__ __align__(16) float obsL[2 * FTILE * 128];

    const int l  = threadIdx.x;
    const bool fw = blockIdx.x < 64;
    const int b  = fw ? blockIdx.x : blockIdx.x - 64;
    const float* obsB = obs + (size_t)b * 4096 * 128;

    h2f eA[64], eB[64];
    if (fw) {
        const int c0 = 2 * l;
        #pragma unroll
        for (int k = 0; k < 64; ++k) {
            h2f ta, tb;
            ta.x = (half_t)__expf(trans[(2*k    ) * 128 + c0]);
            ta.y = (half_t)__expf(trans[(2*k + 1) * 128 + c0]);
            tb.x = (half_t)__expf(trans[(2*k    ) * 128 + c0 + 1]);
            tb.y = (half_t)__expf(trans[(2*k + 1) * 128 + c0 + 1]);
            eA[k] = ta; eB[k] = tb;
        }
    } else {
        const int ro0 = (2 * l) * 128, ro1 = (2 * l + 1) * 128;
        #pragma unroll
        for (int k = 0; k < 64; ++k) {
            h2f ta, tb;
            ta.x = (half_t)__expf(trans[ro0 + 2*k]);
            ta.y = (half_t)__expf(trans[ro0 + 2*k + 1]);
            tb.x = (half_t)__expf(trans[ro1 + 2*k]);
            tb.y = (half_t)__expf(trans[ro1 + 2*k + 1]);
            eA[k] = ta; eB[k] = tb;
        }
    }

    float4 r0, r1, r2, r3, r4, r5, r6, r7;
    FLOADR(0);
    FSTORER(0);
    FLOADR(1);

    float rs = 1.f, Lacc = 0.f, pv0, pv1;

    if (fw) {
        const float2 o2 = *(const float2*)&obsL[l << 1];
        pv0 = __expf(o2.x - SHIFT);
        pv1 = __expf(o2.y - SHIFT);
    } else {
        pv0 = 1.f; pv1 = 1.f;
        FSTEP(0, false, false);
    }

    for (int tile = 0; tile < FNTILE; ++tile) {
        if (tile > 0) {
            FSTORER(tile);
            if (tile < FNTILE - 1) FLOADR(tile + 1);
        }
        const int nb = tile << 4;
        #pragma unroll 1
        for (int g = 0; g < 4; ++g) {
            const int n0 = nb + (g << 2);
            if (n0 > 0) FSTEP(n0, true, false);
            FSTEP(n0 + 1, false, false);
            FSTEP(n0 + 2, false, false);
            if (n0 + 3 != 2047) FSTEP(n0 + 3, false, true);
            else                FSTEP(n0 + 3, false, false);
        }
    }

    if (fw) {
        ws[b * 128 + 2*l]     = pv0;
        ws[b * 128 + 2*l + 1] = pv1;
        if (l == 0) ws[16384 + b] = Lacc;
    } else {
        ws[8192 + b * 128 + 2*l]     = pv0;
        ws[8192 + b * 128 + 2*l + 1] = pv1;
        if (l == 0) ws[16448 + b] = Lacc;
    }
}

__global__ __launch_bounds__(64)
void crf_comb_fb(const float* __restrict__ ws, float* __restrict__ out)
{
    const int b = blockIdx.x, l = threadIdx.x;
    float s = ws[b * 128 + 2*l] * ws[8192 + b * 128 + 2*l]
            + ws[b * 128 + 2*l + 1] * ws[8192 + b * 128 + 2*l + 1];
    s += __shfl_xor(s, 1);  s += __shfl_xor(s, 2);  s += __shfl_xor(s, 4);
    s += __shfl_xor(s, 8);  s += __shfl_xor(s, 16); s += __shfl_xor(s, 32);
    if (l == 0)
        out[b] = -(__logf(s) + ws[16384 + b] + ws[16448 + b] + 4096.0f * SHIFT);
}

// ============================================================================

extern "C" void kernel_launch(void* const* d_in, const int* in_sizes, int n_in,
                              void* d_out, int out_size, void* d_ws, size_t ws_size,
                              hipStream_t stream) {
    (void)in_sizes; (void)n_in; (void)out_size;
    const float* obs   = (const float*)d_in[0];   // [64, 4096, 128] fp32
    const float* trans = (const float*)d_in[1];   // [128, 128] fp32
    float* out = (float*)d_out;                   // [64] fp32
    float* ws  = (float*)d_ws;

    if (ws_size >= (size_t)FAST_WS_BYTES) {
        uint32* eo = (uint32*)((char*)d_ws + EO_BYTE_OFF);
        hipLaunchKernelGGL(eo_prep,  dim3(8192), dim3(256), 0, stream, obs, eo);
        hipLaunchKernelGGL(crf_mfma, dim3(8),    dim3(64),  0, stream, eo, trans, ws);
        hipLaunchKernelGGL(crf_comb, dim3(64),   dim3(64),  0, stream, obs, ws, out);
    } else {
        hipLaunchKernelGGL(crf_half_fb, dim3(128), dim3(64), 0, stream, obs, trans, ws);
        hipLaunchKernelGGL(crf_comb_fb, dim3(64),  dim3(64), 0, stream, ws, out);
    }
}

// Round 7
// 1161.539 us; speedup vs baseline: 1.4808x; 1.0461x over previous
//
#include <hip/hip_runtime.h>

typedef _Float16 half_t;
typedef _Float16 h8 __attribute__((ext_vector_type(8)));
typedef _Float16 h2 __attribute__((ext_vector_type(2)));
typedef float f4 __attribute__((ext_vector_type(4)));
typedef unsigned int uint32;

#define SHIFT16 2.772588722239781f    // log(16), fast path
#define SHIFT8  2.0794415416798357f   // log(8), fallback path
// ws float offsets:  X[64][128] | Q[64][128] | Lf[64] | Lb[64] | pad | eo16
#define WX 0
#define WQ 8192
#define WLF 16384
#define WLB 16448
#define EO_BYTE_OFF 66560u
#define FAST_WS_BYTES (EO_BYTE_OFF + 67108864u)   // eo = 4cg*4096t*64l*64B

__device__ __forceinline__ h2 pkrtz(float a, float b) {
    return __builtin_bit_cast(h2, __builtin_amdgcn_cvt_pkrtz(a, b));
}

// ============================ FAST PATH =====================================

// eo16[cg][t][lane l][hd 0..15 dw]: fp16 exp(obs-SHIFT16) pairs, permuted into
// the per-lane MFMA D-layout order (lane l=q*16+n: chain n, states mt*16+q*4+r;
// dword hd=2mt+(r>>1)). LDS-staged transpose: coalesced reads AND writes.
__global__ __launch_bounds__(256)
void eo_prep(const float* __restrict__ obs, uint32* __restrict__ eo)
{
    __shared__ float sb[64 * 130];       // 64 rows (n,tl) x 128 floats, padded
    const int tid = threadIdx.x;
    const int cg = blockIdx.x >> 10;     // 4 chain-groups
    const int tb = blockIdx.x & 1023;    // 1024 blocks of 4 timesteps

    #pragma unroll
    for (int i = 0; i < 8; ++i) {        // load 64x128 floats, coalesced
        const int idx = i * 256 + tid;   // 2048 float4s
        const int row = idx >> 5, c4 = idx & 31;
        const int n = row >> 2, tl = row & 3;
        const float4 v = *(const float4*)
            &obs[((size_t)(cg * 16 + n) * 4096 + (tb * 4 + tl)) * 128 + c4 * 4];
        *(float4*)&sb[row * 130 + c4 * 4] = v;
    }
    __syncthreads();

    const int l = tid >> 2;              // output lane 0..63
    const int q = l >> 4, nn = l & 15;
    #pragma unroll
    for (int tl = 0; tl < 4; ++tl) {
        uint4 o;
        uint32* po = &o.x;
        #pragma unroll
        for (int j = 0; j < 4; ++j) {
            const int hd = (tid & 3) * 4 + j;
            const int mt = hd >> 1, rr = (hd & 1) * 2;
            const int s = mt * 16 + q * 4 + rr;
            const float* p = &sb[(nn * 4 + tl) * 130 + s];
            po[j] = __builtin_bit_cast(uint32,
                      pkrtz(__expf(p[0] - SHIFT16), __expf(p[1] - SHIFT16)));
        }
        *(uint4*)&eo[((size_t)(cg * 4096 + tb * 4 + tl) << 10) + (tid << 2)] = o;
    }
}

#define TE(N) (FW ? (N) : (4095 - (N)))

template <bool FW, int NIT>
__device__ __forceinline__ void chain(const uint32* __restrict__ eo,
                                      const float* __restrict__ trans,
                                      float* __restrict__ ws,
                                      half_t* Sb, int cg)
{
    const int l = threadIdx.x & 63;
    const int q = l >> 4, n = l & 15;
    const int wbase = (q >> 1) * 128 + n * 8 + 4 * (q & 1);
    const int rbase = q * 128 + n * 8;
    const size_t cgbase = (size_t)cg << 22;

    // exp(A) A-fragments. fwd: D = eA^T*W -> A[m][k]=eA[k][m]; bwd: A[m][k]=eA[m][k]
    h8 Af[8][4];
    #pragma unroll
    for (int mt = 0; mt < 8; ++mt)
        #pragma unroll
        for (int kc = 0; kc < 4; ++kc) {
            h8 a;
            #pragma unroll
            for (int j = 0; j < 8; ++j) {
                const int k = kc * 32 + q * 8 + j;
                const int m = mt * 16 + n;
                a[j] = (half_t)__expf(FW ? trans[k * 128 + m] : trans[m * 128 + k]);
            }
            Af[mt][kc] = a;
        }

    // eo tile registers: er[st*4+c] = lane's dwords (l*16 + c*4 ..+3) at step st.
    uint4 er[16];
    #pragma unroll
    for (int k = 0; k < 16; ++k)
        er[k] = *(const uint4*)(eo + cgbase + ((size_t)TE(k >> 2) << 10)
                                + (l << 4) + ((k & 3) << 2));

    const f4 Z = {0.f, 0.f, 0.f, 0.f};   // hoisted MFMA C-init
    f4 D[8];
    #pragma unroll
    for (int mt = 0; mt < 8; ++mt) D[mt] = (f4){1.f, 1.f, 1.f, 1.f};
    h8 Bf[4];
    float Lacc = 0.f, rs = 1.f;

    #pragma unroll 1
    for (int t = 0; t < 512; ++t) {
        #pragma unroll
        for (int st = 0; st < 4; ++st) {
            const int it = t * 4 + st;
            if ((NIT & 3) != 0 && it >= NIT) continue;   // bwd tail guard

            if (st == 0) {                 // apply pending renorm (fp32, exact)
                #pragma unroll
                for (int mt = 0; mt < 8; ++mt) D[mt] = D[mt] * rs;
            }
            if (st == 3 && it != NIT - 1) {  // measure; shfls overlap this step
                f4 m01 = __builtin_elementwise_max(D[0], D[1]);
                f4 m23 = __builtin_elementwise_max(D[2], D[3]);
                f4 m45 = __builtin_elementwise_max(D[4], D[5]);
                f4 m67 = __builtin_elementwise_max(D[6], D[7]);
                f4 ma = __builtin_elementwise_max(
                            __builtin_elementwise_max(m01, m23),
                            __builtin_elementwise_max(m45, m67));
                float M = fmaxf(fmaxf(ma.x, ma.y), fmaxf(ma.z, ma.w));
                M = fmaxf(M, __shfl_xor(M, 16));
                M = fmaxf(M, __shfl_xor(M, 32));
                Lacc += __logf(M);
                rs = __builtin_amdgcn_rcpf(M);
            }
            // pack W = fp16(D) * eo and publish to Sb
            {
                const uint32* ep = (const uint32*)&er[st * 4];
                #pragma unroll
                for (int mt = 0; mt < 8; ++mt) {
                    h2 w0 = pkrtz(D[mt].x, D[mt].y) * __builtin_bit_cast(h2, ep[2 * mt]);
                    h2 w1 = pkrtz(D[mt].z, D[mt].w) * __builtin_bit_cast(h2, ep[2 * mt + 1]);
                    uint2 wv;
                    wv.x = __builtin_bit_cast(uint32, w0);
                    wv.y = __builtin_bit_cast(uint32, w1);
                    *(uint2*)&Sb[mt * 256 + wbase] = wv;
                }
            }
            // refill consumed eo halves with next tile's data (2-step lookahead;
            // eo is L3-resident so ~400cy latency is covered)
            if (st == 1) {
                #pragma unroll
                for (int k = 0; k < 8; ++k)
                    er[k] = *(const uint4*)(eo + cgbase
                            + ((size_t)TE((t + 1) * 4 + (k >> 2)) << 10)
                            + (l << 4) + ((k & 3) << 2));
            }
            if (st == 3) {
                #pragma unroll
                for (int k = 8; k < 16; ++k)
                    er[k] = *(const uint4*)(eo + cgbase
                            + ((size_t)TE((t + 1) * 4 + (k >> 2)) << 10)
                            + (l << 4) + ((k & 3) << 2));
            }
            // read B fragments and run 32 MFMAs
            #pragma unroll
            for (int kc = 0; kc < 4; ++kc)
                Bf[kc] = __builtin_bit_cast(h8, *(const uint4*)&Sb[kc * 512 + rbase]);
            #pragma unroll
            for (int mt = 0; mt < 8; ++mt) {
                f4 acc = Z;
                acc = __builtin_amdgcn_mfma_f32_16x16x32_f16(Af[mt][0], Bf[0], acc, 0, 0, 0);
                acc = __builtin_amdgcn_mfma_f32_16x16x32_f16(Af[mt][1], Bf[1], acc, 0, 0, 0);
                acc = __builtin_amdgcn_mfma_f32_16x16x32_f16(Af[mt][2], Bf[2], acc, 0, 0, 0);
                acc = __builtin_amdgcn_mfma_f32_16x16x32_f16(Af[mt][3], Bf[3], acc, 0, 0, 0);
                D[mt] = acc;
            }
        }
    }

    float* Xo = ws + (FW ? WX : WQ) + ((cg * 16 + n) << 7);
    #pragma unroll
    for (int mt = 0; mt < 8; ++mt)
        *(f4*)&Xo[mt * 16 + q * 4] = D[mt];
    if (q == 0) ws[(FW ? WLF : WLB) + cg * 16 + n] = Lacc;
}

__global__ __launch_bounds__(64, 1)
void crf_mfma(const uint32* __restrict__ eo, const float* __restrict__ trans,
              float* __restrict__ ws)
{
    __shared__ __align__(16) half_t Sb[2048];   // [chunk 16][chain 16][8 halfs]
    const int bid = blockIdx.x;
    if (bid < 4) chain<true,  2048>(eo, trans, ws, Sb, bid);      // eo 0..2047
    else         chain<false, 2047>(eo, trans, ws, Sb, bid - 4);  // eo 4095..2049
}

// Z = sum_s X[s]*eo_2048[s]*Q[s]; out = -(log Z + Lf + Lb + 4096*SHIFT16)
__global__ __launch_bounds__(64)
void crf_comb(const float* __restrict__ obs, const float* __restrict__ ws,
              float* __restrict__ out)
{
    const int b = blockIdx.x, l = threadIdx.x;
    const int s0 = 2 * l;
    const float2 o = *(const float2*)&obs[((((size_t)b << 12) + 2048) << 7) + s0];
    const float e0 = __expf(o.x - SHIFT16), e1 = __expf(o.y - SHIFT16);
    float v = ws[WX + b * 128 + s0] * e0 * ws[WQ + b * 128 + s0]
            + ws[WX + b * 128 + s0 + 1] * e1 * ws[WQ + b * 128 + s0 + 1];
    v += __shfl_xor(v, 1);  v += __shfl_xor(v, 2);  v += __shfl_xor(v, 4);
    v += __shfl_xor(v, 8);  v += __shfl_xor(v, 16); v += __shfl_xor(v, 32);
    if (l == 0)
        out[b] = -(__logf(v) + ws[WLF + b] + ws[WLB + b] + 4096.0f * SHIFT16);
}

// ======================= FALLBACK (R3, ws too small) ========================

typedef _Float16 h2f __attribute__((ext_vector_type(2)));
#define FTILE 16
#define FNTILE 128

#if __has_builtin(__builtin_amdgcn_fdot2)
#define FDOT2(p, e, acc) __builtin_amdgcn_fdot2((p), (e), (acc), false)
#else
#define FDOT2(p, e, acc) fmaf((float)(p).x, (float)(e).x, fmaf((float)(p).y, (float)(e).y, (acc)))
#endif

__device__ __forceinline__ h2f u2h(uint32 u) { return __builtin_bit_cast(h2f, u); }
__device__ __forceinline__ uint32 f2h(float f) {
    return (uint32)__builtin_bit_cast(unsigned short, (half_t)f);
}

#define FSTEP(N0, APPLY, MEAS)  do {                                                \
    const int row_ = fw ? ((N0) & (FTILE - 1)) : ((FTILE - 1) - ((N0) & (FTILE - 1))); \
    const float2 o2_ = *(const float2*)&obsL[(((N0) >> 4) & 1) * (FTILE * 128) + (row_ << 7) + (l << 1)]; \
    float e0_ = __expf(o2_.x - SHIFT8);                                             \
    float e1_ = __expf(o2_.y - SHIFT8);                                             \
    if (APPLY) { e0_ *= rsf; e1_ *= rsf; }                                          \
    float w0_, w1_;                                                                 \
    if (fw) { w0_ = pv0; w1_ = pv1; } else { w0_ = pv0 * e0_; w1_ = pv1 * e1_; }    \
    Pl[l] = (f2h(w1_) << 16) | f2h(w0_);                                            \
    float a0_=0.f,a1_=0.f,a2_=0.f,a3_=0.f,b0_=0.f,b1_=0.f,b2_=0.f,b3_=0.f;          \
    _Pragma("unroll")                                                               \
    for (int c_ = 0; c_ < 16; ++c_) {                                               \
        const uint4 q_ = ((const uint4*)Pl)[c_];                                    \
        const h2f p0_ = u2h(q_.x), p1_ = u2h(q_.y), p2_ = u2h(q_.z), p3_ = u2h(q_.w); \
        a0_ = FDOT2(p0_, eA[4*c_+0], a0_);                                          \
        a1_ = FDOT2(p1_, eA[4*c_+1], a1_);                                          \
        a2_ = FDOT2(p2_, eA[4*c_+2], a2_);                                          \
        a3_ = FDOT2(p3_, eA[4*c_+3], a3_);                                          \
        b0_ = FDOT2(p0_, eB[4*c_+0], b0_);                                          \
        b1_ = FDOT2(p1_, eB[4*c_+1], b1_);                                          \
        b2_ = FDOT2(p2_, eB[4*c_+2], b2_);                                          \
        b3_ = FDOT2(p3_, eB[4*c_+3], b3_);                                          \
    }                                                                               \
    const float s0_ = (a0_ + a1_) + (a2_ + a3_);                                    \
    const float s1_ = (b0_ + b1_) + (b2_ + b3_);                                    \
    if (fw) { pv0 = s0_ * e0_; pv1 = s1_ * e1_; } else { pv0 = s0_; pv1 = s1_; }    \
    if (MEAS) {                                                                     \
        float m_ = fmaxf(pv0, pv1);                                                 \
        m_ = fmaxf(m_, __shfl_xor(m_, 1));                                          \
        m_ = fmaxf(m_, __shfl_xor(m_, 2));                                          \
        m_ = fmaxf(m_, __shfl_xor(m_, 4));                                          \
        m_ = fmaxf(m_, __shfl_xor(m_, 8));                                          \
        m_ = fmaxf(m_, __shfl_xor(m_, 16));                                         \
        m_ = fmaxf(m_, __shfl_xor(m_, 32));                                         \
        rsf = __builtin_amdgcn_rcpf(m_);                                            \
        Lacc += __logf(m_);                                                         \
    }                                                                               \
} while (0)

#define FLOADR(TK) do {                                                             \
    const float4* g_ = (const float4*)(obsB + (size_t)(fw ? (TK) * (FTILE * 128)    \
                                      : (4096 - FTILE * ((TK) + 1)) * 128));        \
    r0 = g_[l];       r1 = g_[l + 64];  r2 = g_[l + 128]; r3 = g_[l + 192];         \
    r4 = g_[l + 256]; r5 = g_[l + 320]; r6 = g_[l + 384]; r7 = g_[l + 448];         \
} while (0)

#define FSTORER(TK) do {                                                            \
    float4* s_ = (float4*)&obsL[((TK) & 1) * (FTILE * 128)];                        \
    s_[l] = r0;       s_[l + 64] = r1;  s_[l + 128] = r2; s_[l + 192] = r3;         \
    s_[l + 256] = r4; s_[l + 320] = r5; s_[l + 384] = r6; s_[l + 448] = r7;         \
} while (0)

__global__ __launch_bounds__(64, 1)
void crf_half_fb(const float* __restrict__ obs, const float* __restrict__ trans,
                 float* __restrict__ ws)
{
    __shared__ __align__(16) uint32 Pl[64];
    __shared__ __align__(16) float obsL[2 * FTILE * 128];

    const int l  = threadIdx.x;
    const bool fw = blockIdx.x < 64;
    const int b  = fw ? blockIdx.x : blockIdx.x - 64;
    const float* obsB = obs + (size_t)b * 4096 * 128;

    h2f eA[64], eB[64];
    if (fw) {
        const int c0 = 2 * l;
        #pragma unroll
        for (int k = 0; k < 64; ++k) {
            h2f ta, tb;
            ta.x = (half_t)__expf(trans[(2*k    ) * 128 + c0]);
            ta.y = (half_t)__expf(trans[(2*k + 1) * 128 + c0]);
            tb.x = (half_t)__expf(trans[(2*k    ) * 128 + c0 + 1]);
            tb.y = (half_t)__expf(trans[(2*k + 1) * 128 + c0 + 1]);
            eA[k] = ta; eB[k] = tb;
        }
    } else {
        const int ro0 = (2 * l) * 128, ro1 = (2 * l + 1) * 128;
        #pragma unroll
        for (int k = 0; k < 64; ++k) {
            h2f ta, tb;
            ta.x = (half_t)__expf(trans[ro0 + 2*k]);
            ta.y = (half_t)__expf(trans[ro0 + 2*k + 1]);
            tb.x = (half_t)__expf(trans[ro1 + 2*k]);
            tb.y = (half_t)__expf(trans[ro1 + 2*k + 1]);
            eA[k] = ta; eB[k] = tb;
        }
    }

    float4 r0, r1, r2, r3, r4, r5, r6, r7;
    FLOADR(0);
    FSTORER(0);
    FLOADR(1);

    float rsf = 1.f, Lacc = 0.f, pv0, pv1;

    if (fw) {
        const float2 o2 = *(const float2*)&obsL[l << 1];
        pv0 = __expf(o2.x - SHIFT8);
        pv1 = __expf(o2.y - SHIFT8);
    } else {
        pv0 = 1.f; pv1 = 1.f;
        FSTEP(0, false, false);
    }

    for (int tile = 0; tile < FNTILE; ++tile) {
        if (tile > 0) {
            FSTORER(tile);
            if (tile < FNTILE - 1) FLOADR(tile + 1);
        }
        const int nb = tile << 4;
        #pragma unroll 1
        for (int g = 0; g < 4; ++g) {
            const int n0 = nb + (g << 2);
            if (n0 > 0) FSTEP(n0, true, false);
            FSTEP(n0 + 1, false, false);
            FSTEP(n0 + 2, false, false);
            if (n0 + 3 != 2047) FSTEP(n0 + 3, false, true);
            else                FSTEP(n0 + 3, false, false);
        }
    }

    if (fw) {
        ws[b * 128 + 2*l]     = pv0;
        ws[b * 128 + 2*l + 1] = pv1;
        if (l == 0) ws[16384 + b] = Lacc;
    } else {
        ws[8192 + b * 128 + 2*l]     = pv0;
        ws[8192 + b * 128 + 2*l + 1] = pv1;
        if (l == 0) ws[16448 + b] = Lacc;
    }
}

__global__ __launch_bounds__(64)
void crf_comb_fb(const float* __restrict__ ws, float* __restrict__ out)
{
    const int b = blockIdx.x, l = threadIdx.x;
    float s = ws[b * 128 + 2*l] * ws[8192 + b * 128 + 2*l]
            + ws[b * 128 + 2*l + 1] * ws[8192 + b * 128 + 2*l + 1];
    s += __shfl_xor(s, 1);  s += __shfl_xor(s, 2);  s += __shfl_xor(s, 4);
    s += __shfl_xor(s, 8);  s += __shfl_xor(s, 16); s += __shfl_xor(s, 32);
    if (l == 0)
        out[b] = -(__logf(s) + ws[16384 + b] + ws[16448 + b] + 4096.0f * SHIFT8);
}

// ============================================================================

extern "C" void kernel_launch(void* const* d_in, const int* in_sizes, int n_in,
                              void* d_out, int out_size, void* d_ws, size_t ws_size,
                              hipStream_t stream) {
    (void)in_sizes; (void)n_in; (void)out_size;
    const float* obs   = (const float*)d_in[0];   // [64, 4096, 128] fp32
    const float* trans = (const float*)d_in[1];   // [128, 128] fp32
    float* out = (float*)d_out;                   // [64] fp32
    float* ws  = (float*)d_ws;

    if (ws_size >= (size_t)FAST_WS_BYTES) {
        uint32* eo = (uint32*)((char*)d_ws + EO_BYTE_OFF);
        hipLaunchKernelGGL(eo_prep,  dim3(4096), dim3(256), 0, stream, obs, eo);
        hipLaunchKernelGGL(crf_mfma, dim3(8),    dim3(64),  0, stream, eo, trans, ws);
        hipLaunchKernelGGL(crf_comb, dim3(64),   dim3(64),  0, stream, obs, ws, out);
    } else {
        hipLaunchKernelGGL(crf_half_fb, dim3(128), dim3(64), 0, stream, obs, trans, ws);
        hipLaunchKernelGGL(crf_comb_fb, dim3(64),  dim3(64), 0, stream, ws, out);
    }
}